// Round 2
// baseline (2053.429 us; speedup 1.0000x reference)
//
#include <hip/hip_runtime.h>

// LSTM: L=2, B=32, T=256, N=M=1024, gates 4M=4096
// Fused pipelined persistent kernel: 128 blocks (64/layer), layer 1 lags layer
// 0 by one step; gates = [in_t | h_{t-1}] @ [Wih|Whh]^T + b (concat K=2048).
// R2: A-fragments loaded DIRECTLY global->registers (K-split => no inter-wave
// A sharing, LDS staging was pure overhead + 8-way bank conflicts). Counted
// vmcnt waits overlap MFMA with load tail. Cross-wave K-reduction via small
// gred LDS; epilogue reads gred directly (no gfin). Per-layer flag barrier.

typedef __bf16 bf16x8 __attribute__((ext_vector_type(8)));
typedef float  f32x4  __attribute__((ext_vector_type(4)));
typedef unsigned u32x4 __attribute__((ext_vector_type(4)));

__device__ __forceinline__ unsigned short f2bf(float f) {
    union { float f; unsigned u; } v; v.f = f;
    unsigned u = v.u;
    unsigned r = u + 0x7fffu + ((u >> 16) & 1u);   // RNE
    return (unsigned short)(r >> 16);
}
__device__ __forceinline__ float sigmoidf_fast(float x) {
    return 1.0f / (1.0f + __expf(-x));
}
__device__ __forceinline__ float tanhf_fast(float x) {
    return 1.0f - 2.0f / (__expf(2.0f * x) + 1.0f);
}

__global__ void cvt_f32_to_bf16(const float* __restrict__ src,
                                unsigned short* __restrict__ dst, int n4) {
    int i = blockIdx.x * blockDim.x + threadIdx.x;
    int stride = gridDim.x * blockDim.x;
    for (; i < n4; i += stride) {
        float4 v = ((const float4*)src)[i];
        ushort4 o;
        o.x = f2bf(v.x); o.y = f2bf(v.y); o.z = f2bf(v.z); o.w = f2bf(v.w);
        ((ushort4*)dst)[i] = o;
    }
}

// src: (L*4096, 1024) f32 -> dst: (L*4096, 2048) bf16 at column offset `off`
__global__ void cvt_w_concat(const float* __restrict__ src,
                             unsigned short* __restrict__ dst, int off, int n4) {
    int i = blockIdx.x * blockDim.x + threadIdx.x;
    int stride = gridDim.x * blockDim.x;
    for (; i < n4; i += stride) {
        float4 v = ((const float4*)src)[i];
        ushort4 o;
        o.x = f2bf(v.x); o.y = f2bf(v.y); o.z = f2bf(v.z); o.w = f2bf(v.w);
        int row = i >> 8;
        int c4  = i & 255;
        *(ushort4*)&dst[(size_t)row * 2048 + off + c4 * 4] = o;
    }
}

__global__ __launch_bounds__(256, 1) void lstm_fused(
    const unsigned short* __restrict__ Wcat,  // (L,4096,2048) bf16 [Wih|Whh]
    const unsigned short* __restrict__ xbf,   // (B,T,1024) bf16
    unsigned short* __restrict__ seqbf,       // (B,T,1024) bf16 layer0 out
    const unsigned short* __restrict__ h0bf,  // (L,32,1024) bf16 initial h
    unsigned short* __restrict__ hpar,        // (L,2,32,1024) bf16 parity
    const float* __restrict__ c0,             // (L,32,1024) f32 initial c
    const float* __restrict__ bih, const float* __restrict__ bhh,
    float* __restrict__ out, unsigned int* flags)
{
    // K-partials: [kwave][batch-half][col-tile][col n][row pad20]  (40960 B)
    __shared__ __align__(16) float gred[4][2][4][16][20];

    const int tid  = threadIdx.x;
    const int lane = tid & 63;
    const int w    = tid >> 6;
    const int l    = blockIdx.x >> 6;
    const int m0   = (blockIdx.x & 63) * 16;
    const int n    = lane & 15;
    const int lk   = (lane >> 4) * 8;
    const int half = w >> 1;              // 0 = input half, 1 = h half
    const int kbl  = (w & 1) * 512;       // K offset within half
    const int kb   = w * 512;             // global K base (= half*1024 + kbl)

    // ---- persistent weights: wreg[ct*16+kc] = B-frag, col-tile ct, k-step kc
    bf16x8 wreg[64];
    const unsigned short* Wl = Wcat + (size_t)l * 4096 * 2048;
    #pragma unroll
    for (int ct = 0; ct < 4; ct++) {
        int vc = ct * 16 + n;
        size_t jrow = (size_t)((vc & 3) * 1024 + m0 + (vc >> 2));
        #pragma unroll
        for (int kc = 0; kc < 16; kc++)
            wreg[ct * 16 + kc] = *(const bf16x8*)&Wl[jrow * 2048 + kb + kc * 32 + lk];
    }

    // ---- epilogue ownership: thread -> (batch eb, m-pair em,em+1)
    const int eb = lane >> 1;
    const int q  = lane & 1;
    const int em = m0 + 4 * w + 2 * q;
    float bs0[4], bs1[4];
    #pragma unroll
    for (int g = 0; g < 4; g++) {
        bs0[g] = bih[l * 4096 + g * 1024 + em]     + bhh[l * 4096 + g * 1024 + em];
        bs1[g] = bih[l * 4096 + g * 1024 + em + 1] + bhh[l * 4096 + g * 1024 + em + 1];
    }
    float2 creg = *(const float2*)&c0[(size_t)l * 32768 + eb * 1024 + em];
    float2 hlast = {0.f, 0.f};

    const unsigned short* inb = (l == 0) ? xbf : seqbf;
    const bool bypass = (half == 1) || (l == 1);   // h always; seqbf for l=1
    const int uh = eb >> 4, urow = eb & 15;

    #pragma unroll 1
    for (int s = 0; s <= 256; s++) {
        const int  t      = (l == 0) ? s : s - 1;
        const bool active = (l == 0) ? (s < 256) : (s >= 1);

        if (active) {
            // ---- per-iter A-frag bases (row n and row n+16 of K-slice)
            const char *bA, *bB;
            if (half == 0) {
                bA = (const char*)inb + ((size_t)n * 256 + t) * 2048 + (kbl + lk) * 2;
                bB = bA + (size_t)16 * 256 * 2048;
            } else {
                const char* hsrc = (t == 0)
                    ? (const char*)(h0bf + (size_t)l * 32768)
                    : (const char*)(hpar + ((size_t)l * 2 + ((t - 1) & 1)) * 32768);
                bA = hsrc + (size_t)n * 2048 + (kbl + lk) * 2;
                bB = bA + 16 * 2048;
            }

            // ---- issue 32 direct loads in MFMA consumption order
            u32x4 hv[32];
#define LDP_BY(kc, OFF) \
    asm volatile("global_load_dwordx4 %0, %1, off offset:" OFF " sc0 sc1" \
                 : "=v"(hv[2*(kc)]) : "v"(bA) : "memory"); \
    asm volatile("global_load_dwordx4 %0, %1, off offset:" OFF " sc0 sc1" \
                 : "=v"(hv[2*(kc)+1]) : "v"(bB) : "memory");
#define LDP_CA(kc, OFF) \
    asm volatile("global_load_dwordx4 %0, %1, off offset:" OFF \
                 : "=v"(hv[2*(kc)]) : "v"(bA) : "memory"); \
    asm volatile("global_load_dwordx4 %0, %1, off offset:" OFF \
                 : "=v"(hv[2*(kc)+1]) : "v"(bB) : "memory");
            if (bypass) {
                LDP_BY(0,"0")    LDP_BY(1,"64")   LDP_BY(2,"128")  LDP_BY(3,"192")
                LDP_BY(4,"256")  LDP_BY(5,"320")  LDP_BY(6,"384")  LDP_BY(7,"448")
                LDP_BY(8,"512")  LDP_BY(9,"576")  LDP_BY(10,"640") LDP_BY(11,"704")
                LDP_BY(12,"768") LDP_BY(13,"832") LDP_BY(14,"896") LDP_BY(15,"960")
            } else {
                LDP_CA(0,"0")    LDP_CA(1,"64")   LDP_CA(2,"128")  LDP_CA(3,"192")
                LDP_CA(4,"256")  LDP_CA(5,"320")  LDP_CA(6,"384")  LDP_CA(7,"448")
                LDP_CA(8,"512")  LDP_CA(9,"576")  LDP_CA(10,"640") LDP_CA(11,"704")
                LDP_CA(12,"768") LDP_CA(13,"832") LDP_CA(14,"896") LDP_CA(15,"960")
            }

            // ---- MFMA, 4 groups of 4 k-steps, counted vmcnt overlap
            f32x4 acc0[4] = {}, acc1[4] = {};
#define MFMA_K(kc) { \
    bf16x8 a0 = __builtin_bit_cast(bf16x8, hv[2*(kc)]); \
    bf16x8 a1 = __builtin_bit_cast(bf16x8, hv[2*(kc)+1]); \
    _Pragma("unroll") \
    for (int ct = 0; ct < 4; ct++) { \
        acc0[ct] = __builtin_amdgcn_mfma_f32_16x16x32_bf16(a0, wreg[ct*16+(kc)], acc0[ct], 0, 0, 0); \
        acc1[ct] = __builtin_amdgcn_mfma_f32_16x16x32_bf16(a1, wreg[ct*16+(kc)], acc1[ct], 0, 0, 0); \
    } }
            asm volatile("s_waitcnt vmcnt(24)" ::: "memory");
            __builtin_amdgcn_sched_barrier(0);
            MFMA_K(0)  MFMA_K(1)  MFMA_K(2)  MFMA_K(3)
            asm volatile("s_waitcnt vmcnt(16)" ::: "memory");
            __builtin_amdgcn_sched_barrier(0);
            MFMA_K(4)  MFMA_K(5)  MFMA_K(6)  MFMA_K(7)
            asm volatile("s_waitcnt vmcnt(8)" ::: "memory");
            __builtin_amdgcn_sched_barrier(0);
            MFMA_K(8)  MFMA_K(9)  MFMA_K(10) MFMA_K(11)
            asm volatile("s_waitcnt vmcnt(0)" ::: "memory");
            __builtin_amdgcn_sched_barrier(0);
            MFMA_K(12) MFMA_K(13) MFMA_K(14) MFMA_K(15)

            // ---- write K-partials (C/D layout: col=n, rows r0..r0+3)
            {
                int r0 = (lane >> 4) * 4;
                #pragma unroll
                for (int ct = 0; ct < 4; ct++) {
                    *(f32x4*)&gred[w][0][ct][n][r0] = acc0[ct];
                    *(f32x4*)&gred[w][1][ct][n][r0] = acc1[ct];
                }
            }
            __syncthreads();   // partials visible

            // ---- reduce + epilogue: thread's 8 gate cols are ct=w, n=8q+j
            float g8[8];
            #pragma unroll
            for (int j = 0; j < 8; j++) {
                g8[j] = (gred[0][uh][w][8 * q + j][urow] + gred[1][uh][w][8 * q + j][urow])
                      + (gred[2][uh][w][8 * q + j][urow] + gred[3][uh][w][8 * q + j][urow]);
            }
            float gi0 = g8[0] + bs0[0], gf0 = g8[1] + bs0[1];
            float gg0 = g8[2] + bs0[2], go0 = g8[3] + bs0[3];
            float gi1 = g8[4] + bs1[0], gf1 = g8[5] + bs1[1];
            float gg1 = g8[6] + bs1[2], go1 = g8[7] + bs1[3];

            float c0n = sigmoidf_fast(gf0) * creg.x + sigmoidf_fast(gi0) * tanhf_fast(gg0);
            float c1n = sigmoidf_fast(gf1) * creg.y + sigmoidf_fast(gi1) * tanhf_fast(gg1);
            float h0v = sigmoidf_fast(go0) * tanhf_fast(c0n);
            float h1v = sigmoidf_fast(go1) * tanhf_fast(c1n);
            creg.x = c0n; creg.y = c1n;
            hlast.x = h0v; hlast.y = h1v;

            unsigned hp = (unsigned)f2bf(h0v) | ((unsigned)f2bf(h1v) << 16);
            __hip_atomic_store(
                (unsigned*)&hpar[((size_t)l * 2 + (t & 1)) * 32768 + eb * 1024 + em],
                hp, __ATOMIC_RELAXED, __HIP_MEMORY_SCOPE_AGENT);
            if (l == 0) {
                __hip_atomic_store(
                    (unsigned*)&seqbf[((size_t)eb * 256 + t) * 1024 + em],
                    hp, __ATOMIC_RELAXED, __HIP_MEMORY_SCOPE_AGENT);
            } else {
                float2 hv2 = {h0v, h1v};
                *(float2*)&out[((size_t)eb * 256 + t) * 1024 + em] = hv2;
            }
        }

        // ---- per-layer distributed barrier
        asm volatile("s_waitcnt vmcnt(0)" ::: "memory");
        __syncthreads();
        {
            const unsigned tgt = (unsigned)(s + 1);
            if (tid == 0)
                __hip_atomic_store(flags + (size_t)blockIdx.x * 32, tgt,
                                   __ATOMIC_RELAXED, __HIP_MEMORY_SCOPE_AGENT);
            if (tid < 64) {
                // own layer: 64 lines
                const unsigned* fp = flags + (size_t)(l * 64 + tid) * 32;
                while (true) {
                    unsigned v = __hip_atomic_load(fp, __ATOMIC_RELAXED,
                                                   __HIP_MEMORY_SCOPE_AGENT);
                    if (__all((int)(v >= tgt))) break;
                    __builtin_amdgcn_s_sleep(1);
                }
            } else if (l == 1 && tid < 128) {
                // layer-1 also needs layer-0 progress (seqbf[t=s])
                const unsigned* fp = flags + (size_t)(tid - 64) * 32;
                while (true) {
                    unsigned v = __hip_atomic_load(fp, __ATOMIC_RELAXED,
                                                   __HIP_MEMORY_SCOPE_AGENT);
                    if (__all((int)(v >= tgt))) break;
                    __builtin_amdgcn_s_sleep(1);
                }
            }
        }
        __syncthreads();
    }

    // ---- final states
    float* hF = out + (size_t)8192 * 1024 + (size_t)l * 32768;
    float* cF = out + (size_t)8192 * 1024 + 65536 + (size_t)l * 32768;
    float2 hf2 = {hlast.x, hlast.y};
    *(float2*)&hF[eb * 1024 + em] = hf2;
    float2 cf2 = {creg.x, creg.y};
    *(float2*)&cF[eb * 1024 + em] = cf2;
}

extern "C" void kernel_launch(void* const* d_in, const int* in_sizes, int n_in,
                              void* d_out, int out_size, void* d_ws, size_t ws_size,
                              hipStream_t stream)
{
    const float* x   = (const float*)d_in[0];
    const float* h0  = (const float*)d_in[1];
    const float* c0  = (const float*)d_in[2];
    const float* Wih = (const float*)d_in[3];
    const float* Whh = (const float*)d_in[4];
    const float* bih = (const float*)d_in[5];
    const float* bhh = (const float*)d_in[6];
    float* out = (float*)d_out;

    char* p = (char*)d_ws;
    unsigned short* xbf   = (unsigned short*)p; p += (size_t)8192 * 1024 * 2;      // 16 MB
    unsigned short* seqbf = (unsigned short*)p; p += (size_t)8192 * 1024 * 2;      // 16 MB
    unsigned short* Wcat  = (unsigned short*)p; p += (size_t)2 * 4096 * 2048 * 2;  // 32 MB
    unsigned short* hbfA  = (unsigned short*)p; p += (size_t)2 * 32 * 1024 * 2;    // 128 KB
    unsigned short* hpar  = (unsigned short*)p; p += (size_t)2 * 2 * 32 * 1024 * 2;// 256 KB
    unsigned int*   flags = (unsigned int*)p;   p += 128 * 128;                    // 16 KB

    hipMemsetAsync(flags, 0, 128 * 128, stream);
    cvt_f32_to_bf16<<<1024, 256, 0, stream>>>(x,  xbf,  8192 * 1024 / 4);
    cvt_f32_to_bf16<<<64,   256, 0, stream>>>(h0, hbfA, 2 * 32 * 1024 / 4);
    cvt_w_concat<<<1024, 256, 0, stream>>>(Wih, Wcat, 0,    2 * 4096 * 256);
    cvt_w_concat<<<1024, 256, 0, stream>>>(Whh, Wcat, 1024, 2 * 4096 * 256);

    lstm_fused<<<128, 256, 0, stream>>>(Wcat, xbf, seqbf, hbfA, hpar,
                                        c0, bih, bhh, out, flags);
}

// Round 3
// 1751.932 us; speedup vs baseline: 1.1721x; 1.1721x over previous
//
#include <hip/hip_runtime.h>

// LSTM: L=2, B=32, T=256, N=M=1024, gates 4M=4096
// R3: fused persistent pipeline, 128 blocks (64/layer), layer-1 lag = 2.
// Critical path per iteration = h-half GEMM only (K=1024): 16 coalesced bypass
// loads -> swizzled LDS -> 64 MFMA. The x/seq-half GEMM (K=1024) runs AFTER
// the flag store, BEFORE the poll (overlaps peer skew); its partials live in
// the accumulators across the barrier. Flags packed at 4B stride so the
// 64-block gather-poll touches 4 cache lines instead of 64.

typedef __bf16 bf16x8 __attribute__((ext_vector_type(8)));
typedef float  f32x4  __attribute__((ext_vector_type(4)));
typedef unsigned u32x4 __attribute__((ext_vector_type(4)));

__device__ __forceinline__ unsigned short f2bf(float f) {
    union { float f; unsigned u; } v; v.f = f;
    unsigned u = v.u;
    unsigned r = u + 0x7fffu + ((u >> 16) & 1u);   // RNE
    return (unsigned short)(r >> 16);
}
__device__ __forceinline__ float sigmoidf_fast(float x) {
    return 1.0f / (1.0f + __expf(-x));
}
__device__ __forceinline__ float tanhf_fast(float x) {
    return 1.0f - 2.0f / (__expf(2.0f * x) + 1.0f);
}

__global__ void cvt_f32_to_bf16(const float* __restrict__ src,
                                unsigned short* __restrict__ dst, int n4) {
    int i = blockIdx.x * blockDim.x + threadIdx.x;
    int stride = gridDim.x * blockDim.x;
    for (; i < n4; i += stride) {
        float4 v = ((const float4*)src)[i];
        ushort4 o;
        o.x = f2bf(v.x); o.y = f2bf(v.y); o.z = f2bf(v.z); o.w = f2bf(v.w);
        ((ushort4*)dst)[i] = o;
    }
}

// src: (L*4096, 1024) f32 -> dst: (L*4096, 2048) bf16 at column offset `off`
__global__ void cvt_w_concat(const float* __restrict__ src,
                             unsigned short* __restrict__ dst, int off, int n4) {
    int i = blockIdx.x * blockDim.x + threadIdx.x;
    int stride = gridDim.x * blockDim.x;
    for (; i < n4; i += stride) {
        float4 v = ((const float4*)src)[i];
        ushort4 o;
        o.x = f2bf(v.x); o.y = f2bf(v.y); o.z = f2bf(v.z); o.w = f2bf(v.w);
        int row = i >> 8;
        int c4  = i & 255;
        *(ushort4*)&dst[(size_t)row * 2048 + off + c4 * 4] = o;
    }
}

__global__ __launch_bounds__(256, 1) void lstm_fused(
    const unsigned short* __restrict__ Wcat,  // (L,4096,2048) bf16 [Wih|Whh]
    const unsigned short* __restrict__ xbf,   // (B,T,1024) bf16
    unsigned short* __restrict__ seqbf,       // (B,T,1024) bf16 layer0 out
    const unsigned short* __restrict__ h0bf,  // (L,32,1024) bf16 initial h
    unsigned short* __restrict__ hpar,        // (L,2,32,1024) bf16 parity
    const float* __restrict__ c0,             // (L,32,1024) f32 initial c
    const float* __restrict__ bih, const float* __restrict__ bhh,
    float* __restrict__ out, unsigned int* flags)   // flags: [2][64] packed u32
{
    __shared__ __align__(16) unsigned short hsh[32][1024];  // 64 KB, swizzled
    __shared__ __align__(16) float gred[4][2][4][16][20];   // 40 KB

    const int tid  = threadIdx.x;
    const int lane = tid & 63;
    const int w    = tid >> 6;
    const int l    = blockIdx.x >> 6;
    const int bidl = blockIdx.x & 63;
    const int m0   = bidl * 16;
    const int n    = lane & 15;
    const int g    = lane >> 4;          // k-chunk group 0..3
    const int lk   = g * 8;
    const int nn7  = n & 7;

    // ---- persistent weights (AGPR-resident): x-half and h-half K-slices
    bf16x8 wx[32], wh[32];
    const unsigned short* Wl = Wcat + (size_t)l * 4096 * 2048;
    #pragma unroll
    for (int ct = 0; ct < 4; ct++) {
        int vc = ct * 16 + n;
        size_t jrow = (size_t)((vc & 3) * 1024 + m0 + (vc >> 2));
        #pragma unroll
        for (int kc = 0; kc < 8; kc++) {
            wx[ct*8+kc] = *(const bf16x8*)&Wl[jrow*2048 +        w*256 + kc*32 + lk];
            wh[ct*8+kc] = *(const bf16x8*)&Wl[jrow*2048 + 1024 + w*256 + kc*32 + lk];
        }
    }

    // ---- epilogue ownership: thread -> (batch eb, m-pair em,em+1)
    const int eb = lane >> 1;
    const int q  = lane & 1;
    const int em = m0 + 4 * w + 2 * q;
    float bs0[4], bs1[4];
    #pragma unroll
    for (int gg = 0; gg < 4; gg++) {
        bs0[gg] = bih[l*4096 + gg*1024 + em]     + bhh[l*4096 + gg*1024 + em];
        bs1[gg] = bih[l*4096 + gg*1024 + em + 1] + bhh[l*4096 + gg*1024 + em + 1];
    }
    float2 creg = *(const float2*)&c0[(size_t)l * 32768 + eb * 1024 + em];
    float2 hlast = {0.f, 0.f};
    const int uh = eb >> 4, urow = eb & 15;

    // staging geometry
    const int srow = tid >> 7;           // 0/1
    const int scol = tid & 127;          // 16B unit within 2048B row

    // LDS read bases (bytes): row n / n+16, this wave's 512B K-window
    char* const hshb = (char*)&hsh[0][0];
    const char* rA = hshb + n * 2048 + w * 512 + g * 16;
    const char* rB = rA + 16 * 2048;

    f32x4 acc0[4] = {}, acc1[4] = {};
    const unsigned short* xsrc = (l == 0) ? xbf : seqbf;

    // ================= x/seq-half GEMM (off critical path) =================
#define XLD_C(kc, OFF) \
    asm volatile("global_load_dwordx4 %0, %1, off offset:" OFF \
                 : "=v"(hx[2*(kc)]) : "v"(xA) : "memory"); \
    asm volatile("global_load_dwordx4 %0, %1, off offset:" OFF \
                 : "=v"(hx[2*(kc)+1]) : "v"(xB) : "memory");
#define XLD_B(kc, OFF) \
    asm volatile("global_load_dwordx4 %0, %1, off offset:" OFF " sc0 sc1" \
                 : "=v"(hx[2*(kc)]) : "v"(xA) : "memory"); \
    asm volatile("global_load_dwordx4 %0, %1, off offset:" OFF " sc0 sc1" \
                 : "=v"(hx[2*(kc)+1]) : "v"(xB) : "memory");
#define XMFMA(kc) { \
    bf16x8 a0 = __builtin_bit_cast(bf16x8, hx[2*(kc)]); \
    bf16x8 a1 = __builtin_bit_cast(bf16x8, hx[2*(kc)+1]); \
    _Pragma("unroll") \
    for (int ct = 0; ct < 4; ct++) { \
        acc0[ct] = __builtin_amdgcn_mfma_f32_16x16x32_bf16(a0, wx[ct*8+(kc)], acc0[ct], 0,0,0); \
        acc1[ct] = __builtin_amdgcn_mfma_f32_16x16x32_bf16(a1, wx[ct*8+(kc)], acc1[ct], 0,0,0); \
    } }
    auto xphase = [&](int tn) {
        const char* xA = (const char*)xsrc + ((size_t)n * 256 + tn) * 2048
                       + (w * 512 + g * 16);
        const char* xB = xA + (size_t)16 * 256 * 2048;
        u32x4 hx[16];
        if (l == 0) {
            XLD_C(0,"0")   XLD_C(1,"64")  XLD_C(2,"128") XLD_C(3,"192")
            XLD_C(4,"256") XLD_C(5,"320") XLD_C(6,"384") XLD_C(7,"448")
        } else {
            XLD_B(0,"0")   XLD_B(1,"64")  XLD_B(2,"128") XLD_B(3,"192")
            XLD_B(4,"256") XLD_B(5,"320") XLD_B(6,"384") XLD_B(7,"448")
        }
        #pragma unroll
        for (int ct = 0; ct < 4; ct++) {
            acc0[ct] = (f32x4){0.f, 0.f, 0.f, 0.f};
            acc1[ct] = (f32x4){0.f, 0.f, 0.f, 0.f};
        }
        asm volatile("s_waitcnt vmcnt(8)" ::: "memory");
        __builtin_amdgcn_sched_barrier(0);
        XMFMA(0) XMFMA(1) XMFMA(2) XMFMA(3)
        asm volatile("s_waitcnt vmcnt(0)" ::: "memory");
        __builtin_amdgcn_sched_barrier(0);
        XMFMA(4) XMFMA(5) XMFMA(6) XMFMA(7)
    };

    // prologue: L0's first input tile (t=0)
    if (l == 0) xphase(0);

    #pragma unroll 1
    for (int s = 0; s <= 257; s++) {
        const int  t      = (l == 0) ? s : s - 2;
        const bool active = (l == 0) ? (s < 256) : (s >= 2);

        if (active) {
            // ---- stage h(t-1): 16 coalesced bypass loads -> swizzled LDS
            const char* hb = (t == 0)
                ? (const char*)(h0bf + (size_t)l * 32768)
                : (const char*)(hpar + ((size_t)l * 2 + ((t - 1) & 1)) * 32768);
            const char* hp0 = hb + srow * 2048 + scol * 16;
            u32x4 hvh[16];
            #pragma unroll
            for (int si = 0; si < 16; si++) {
                const void* ap = hp0 + si * 4096;
                asm volatile("global_load_dwordx4 %0, %1, off sc0 sc1"
                             : "=v"(hvh[si]) : "v"(ap) : "memory");
            }
            asm volatile("s_waitcnt vmcnt(0)" ::: "memory");
            #pragma unroll
            for (int si = 0; si < 16; si++) {
                int row = 2 * si + srow;
                *(u32x4*)(hshb + row * 2048 + ((scol * 16) ^ ((row & 7) << 6))) = hvh[si];
            }
            __syncthreads();   // sync1: tile staged

            // ---- h-half GEMM on top of x-partials already in acc
            #pragma unroll
            for (int kc = 0; kc < 8; kc++) {
                bf16x8 a0 = *(const bf16x8*)(rA + ((kc ^ nn7) << 6));
                bf16x8 a1 = *(const bf16x8*)(rB + ((kc ^ nn7) << 6));
                #pragma unroll
                for (int ct = 0; ct < 4; ct++) {
                    acc0[ct] = __builtin_amdgcn_mfma_f32_16x16x32_bf16(
                        a0, wh[ct*8+kc], acc0[ct], 0, 0, 0);
                    acc1[ct] = __builtin_amdgcn_mfma_f32_16x16x32_bf16(
                        a1, wh[ct*8+kc], acc1[ct], 0, 0, 0);
                }
            }

            // ---- K-partials -> LDS
            {
                int r0 = (lane >> 4) * 4;
                #pragma unroll
                for (int ct = 0; ct < 4; ct++) {
                    *(f32x4*)&gred[w][0][ct][n][r0] = acc0[ct];
                    *(f32x4*)&gred[w][1][ct][n][r0] = acc1[ct];
                }
            }
            __syncthreads();   // sync2: partials visible

            // ---- reduce + epilogue: thread's 8 gate cols: ct=w, n=8q+j
            float g8[8];
            #pragma unroll
            for (int j = 0; j < 8; j++) {
                g8[j] = (gred[0][uh][w][8*q+j][urow] + gred[1][uh][w][8*q+j][urow])
                      + (gred[2][uh][w][8*q+j][urow] + gred[3][uh][w][8*q+j][urow]);
            }
            float gi0 = g8[0] + bs0[0], gf0 = g8[1] + bs0[1];
            float gg0 = g8[2] + bs0[2], go0 = g8[3] + bs0[3];
            float gi1 = g8[4] + bs1[0], gf1 = g8[5] + bs1[1];
            float gg1 = g8[6] + bs1[2], go1 = g8[7] + bs1[3];

            float c0n = sigmoidf_fast(gf0) * creg.x + sigmoidf_fast(gi0) * tanhf_fast(gg0);
            float c1n = sigmoidf_fast(gf1) * creg.y + sigmoidf_fast(gi1) * tanhf_fast(gg1);
            float h0v = sigmoidf_fast(go0) * tanhf_fast(c0n);
            float h1v = sigmoidf_fast(go1) * tanhf_fast(c1n);
            creg.x = c0n; creg.y = c1n;
            hlast.x = h0v; hlast.y = h1v;

            unsigned hp = (unsigned)f2bf(h0v) | ((unsigned)f2bf(h1v) << 16);
            __hip_atomic_store(
                (unsigned*)&hpar[((size_t)l * 2 + (t & 1)) * 32768 + eb * 1024 + em],
                hp, __ATOMIC_RELAXED, __HIP_MEMORY_SCOPE_AGENT);
            if (l == 0) {
                __hip_atomic_store(
                    (unsigned*)&seqbf[((size_t)eb * 256 + t) * 1024 + em],
                    hp, __ATOMIC_RELAXED, __HIP_MEMORY_SCOPE_AGENT);
            } else {
                float2 hv2 = {h0v, h1v};
                *(float2*)&out[((size_t)eb * 256 + t) * 1024 + em] = hv2;
            }
            asm volatile("s_waitcnt vmcnt(0)" ::: "memory");  // drain stores
            __syncthreads();   // sync3: whole block drained
        }

        // ---- arrive
        if (tid == 0)
            __hip_atomic_store(flags + l * 64 + bidl, (unsigned)(s + 1),
                               __ATOMIC_RELAXED, __HIP_MEMORY_SCOPE_AGENT);

        // ---- next-iteration input-half GEMM (overlaps peer skew)
        {
            const int tn = (l == 0) ? s + 1 : s - 1;
            const bool xact = (l == 0) ? (s <= 254) : (s >= 1 && s <= 256);
            if (xact) xphase(tn);
        }

        // ---- gather-poll packed flags (4 cache lines per layer)
        {
            const unsigned tgt = (unsigned)(s + 1);
            if (tid < 64) {
                const unsigned* fp = flags + l * 64 + tid;
                while (true) {
                    unsigned v = __hip_atomic_load(fp, __ATOMIC_RELAXED,
                                                   __HIP_MEMORY_SCOPE_AGENT);
                    if (__all((int)(v >= tgt))) break;
                    __builtin_amdgcn_s_sleep(1);
                }
            } else if (l == 1 && tid < 128) {
                const unsigned* fp = flags + (tid - 64);   // layer-0 flags
                while (true) {
                    unsigned v = __hip_atomic_load(fp, __ATOMIC_RELAXED,
                                                   __HIP_MEMORY_SCOPE_AGENT);
                    if (__all((int)(v >= tgt))) break;
                    __builtin_amdgcn_s_sleep(1);
                }
            }
        }
        __syncthreads();   // sync4: barrier joined
    }

    // ---- final states
    float* hF = out + (size_t)8192 * 1024 + (size_t)l * 32768;
    float* cF = out + (size_t)8192 * 1024 + 65536 + (size_t)l * 32768;
    float2 hf2 = {hlast.x, hlast.y};
    *(float2*)&hF[eb * 1024 + em] = hf2;
    float2 cf2 = {creg.x, creg.y};
    *(float2*)&cF[eb * 1024 + em] = cf2;
}

extern "C" void kernel_launch(void* const* d_in, const int* in_sizes, int n_in,
                              void* d_out, int out_size, void* d_ws, size_t ws_size,
                              hipStream_t stream)
{
    const float* x   = (const float*)d_in[0];
    const float* h0  = (const float*)d_in[1];
    const float* c0  = (const float*)d_in[2];
    const float* Wih = (const float*)d_in[3];
    const float* Whh = (const float*)d_in[4];
    const float* bih = (const float*)d_in[5];
    const float* bhh = (const float*)d_in[6];
    float* out = (float*)d_out;

    char* p = (char*)d_ws;
    unsigned short* xbf   = (unsigned short*)p; p += (size_t)8192 * 1024 * 2;      // 16 MB
    unsigned short* seqbf = (unsigned short*)p; p += (size_t)8192 * 1024 * 2;      // 16 MB
    unsigned short* Wcat  = (unsigned short*)p; p += (size_t)2 * 4096 * 2048 * 2;  // 32 MB
    unsigned short* hbfA  = (unsigned short*)p; p += (size_t)2 * 32 * 1024 * 2;    // 128 KB
    unsigned short* hpar  = (unsigned short*)p; p += (size_t)2 * 2 * 32 * 1024 * 2;// 256 KB
    unsigned int*   flags = (unsigned int*)p;   p += 4096;                         // 2x64 packed

    hipMemsetAsync(flags, 0, 4096, stream);
    cvt_f32_to_bf16<<<1024, 256, 0, stream>>>(x,  xbf,  8192 * 1024 / 4);
    cvt_f32_to_bf16<<<64,   256, 0, stream>>>(h0, hbfA, 2 * 32 * 1024 / 4);
    cvt_w_concat<<<1024, 256, 0, stream>>>(Wih, Wcat, 0,    2 * 4096 * 256);
    cvt_w_concat<<<1024, 256, 0, stream>>>(Whh, Wcat, 1024, 2 * 4096 * 256);

    lstm_fused<<<128, 256, 0, stream>>>(Wcat, xbf, seqbf, hbfA, hpar,
                                        c0, bih, bhh, out, flags);
}

// Round 5
// 1448.800 us; speedup vs baseline: 1.4173x; 1.2092x over previous
//
#include <hip/hip_runtime.h>

// LSTM: L=2, B=32, T=256, N=M=1024, gates 4M=4096
// R5: R4's tile data path + R1/R2-proven strict lockstep barrier.
// 128 blocks (64/layer), layer-1 lag = 2. Per iteration s:
//   act (t = s-lag): stage h(t-1) [64KB coalesced bypass -> swizzled LDS],
//     h-GEMM on top of x-partials, gred reduce, epilogue, coalesced 1KB
//     exchange store (wave 0) + drain, flag = s+1.
//   tail (tn = t+1): stage x/seq tile tn (published <= iter s-1), x-GEMM
//     partials for next step.
//   poll ALL 128 packed flags >= s+1 (2 waves x 4 cache lines), barrier.

typedef __bf16 bf16x8 __attribute__((ext_vector_type(8)));
typedef float  f32x4  __attribute__((ext_vector_type(4)));
typedef unsigned u32x4 __attribute__((ext_vector_type(4)));

__device__ __forceinline__ unsigned short f2bf(float f) {
    union { float f; unsigned u; } v; v.f = f;
    unsigned u = v.u;
    unsigned r = u + 0x7fffu + ((u >> 16) & 1u);   // RNE
    return (unsigned short)(r >> 16);
}
__device__ __forceinline__ float sigmoidf_fast(float x) {
    return 1.0f / (1.0f + __expf(-x));
}
__device__ __forceinline__ float tanhf_fast(float x) {
    return 1.0f - 2.0f / (__expf(2.0f * x) + 1.0f);
}

// src: (L*4096, 1024) f32 -> dst: (L*4096, 2048) bf16 at column offset `off`
__global__ void cvt_w_concat(const float* __restrict__ src,
                             unsigned short* __restrict__ dst, int off, int n4) {
    int i = blockIdx.x * blockDim.x + threadIdx.x;
    int stride = gridDim.x * blockDim.x;
    for (; i < n4; i += stride) {
        float4 v = ((const float4*)src)[i];
        ushort4 o;
        o.x = f2bf(v.x); o.y = f2bf(v.y); o.z = f2bf(v.z); o.w = f2bf(v.w);
        int row = i >> 8;
        int c4  = i & 255;
        *(ushort4*)&dst[(size_t)row * 2048 + off + c4 * 4] = o;
    }
}

// x (B,T,N) f32 -> per-t tiles [t][blk 64][b 32][mi 16] bf16; one block per t
__global__ void cvt_x_tiles(const float* __restrict__ x,
                            unsigned short* __restrict__ xT) {
    int t = blockIdx.x, tid = threadIdx.x;
    unsigned short* tile = xT + (size_t)t * 32768;
    for (int b = 0; b < 32; ++b) {
        float4 v = *(const float4*)&x[((size_t)b * 256 + t) * 1024 + tid * 4];
        ushort4 o;
        o.x = f2bf(v.x); o.y = f2bf(v.y); o.z = f2bf(v.z); o.w = f2bf(v.w);
        *(ushort4*)&tile[(tid >> 2) * 512 + b * 16 + (tid & 3) * 4] = o;
    }
}

// h0 (L,B,M) f32 -> tiles [l][blk][b][mi] bf16; one block per l
__global__ void cvt_h0_tiles(const float* __restrict__ h0,
                             unsigned short* __restrict__ h0T) {
    int l = blockIdx.x, tid = threadIdx.x;
    unsigned short* tile = h0T + (size_t)l * 32768;
    for (int b = 0; b < 32; ++b) {
        float4 v = *(const float4*)&h0[((size_t)l * 32 + b) * 1024 + tid * 4];
        ushort4 o;
        o.x = f2bf(v.x); o.y = f2bf(v.y); o.z = f2bf(v.z); o.w = f2bf(v.w);
        *(ushort4*)&tile[(tid >> 2) * 512 + b * 16 + (tid & 3) * 4] = o;
    }
}

// outT [t][blk][b][mi] f32 -> out (B,T,M) f32; one block per t
__global__ void out_transpose(const float* __restrict__ outT,
                              float* __restrict__ out) {
    int t = blockIdx.x, tid = threadIdx.x;
    const float* tile = outT + (size_t)t * 32768;
    for (int b = 0; b < 32; ++b) {
        float4 v = *(const float4*)&tile[(tid >> 2) * 512 + b * 16 + (tid & 3) * 4];
        *(float4*)&out[((size_t)b * 256 + t) * 1024 + tid * 4] = v;
    }
}

__device__ __forceinline__ void pollge(const unsigned* fp, unsigned tgt) {
    while (true) {
        unsigned v = __hip_atomic_load(fp, __ATOMIC_RELAXED,
                                       __HIP_MEMORY_SCOPE_AGENT);
        if (__all((int)(v >= tgt))) break;
        __builtin_amdgcn_s_sleep(1);
    }
}

#define STAGE_LOADS(FLAGS_STR) \
    _Pragma("unroll") \
    for (int si = 0; si < 16; si++) \
        asm volatile("global_load_dwordx4 %0, %1, off" FLAGS_STR \
                     : "=v"(hv[si]) : "v"(gp + si * 4096) : "memory");

__global__ __launch_bounds__(256, 1) void lstm_fused(
    const unsigned short* __restrict__ Wcat,  // (L,4096,2048) bf16 [Wih|Whh]
    const unsigned short* __restrict__ xT,    // 256 x 64KB tiles bf16
    unsigned short* __restrict__ seqT,        // 256 x 64KB tiles (layer0 h)
    const unsigned short* __restrict__ h0T,   // 2 x 64KB tiles
    unsigned short* __restrict__ hparT,       // 2 x 64KB tiles (layer1 parity)
    float* __restrict__ outT,                 // 256 x 128KB f32 tiles
    const float* __restrict__ c0,             // (L,32,1024) f32
    const float* __restrict__ bih, const float* __restrict__ bhh,
    float* __restrict__ out, unsigned int* flags)   // flags: [2][64] u32 packed
{
    __shared__ __align__(16) unsigned short buf[32][1024];   // 64KB swizzled
    __shared__ __align__(16) float gred[4][2][4][16][20];    // 40KB
    __shared__ __align__(16) unsigned short hout_bf[32][16]; // 1KB
    __shared__ __align__(16) float hout_f[32][16];           // 2KB

    const int tid  = threadIdx.x;
    const int lane = tid & 63;
    const int w    = tid >> 6;
    const int l    = blockIdx.x >> 6;
    const int bidl = blockIdx.x & 63;
    const int m0   = bidl * 16;
    const int n    = lane & 15;
    const int g    = lane >> 4;
    const int lk   = g * 8;
    const int nn7  = n & 7;

    // ---- persistent weights: wave w owns K-window [w*256,+256) in each half
    bf16x8 wx[32], wh[32];
    const unsigned short* Wl = Wcat + (size_t)l * 4096 * 2048;
    #pragma unroll
    for (int ct = 0; ct < 4; ct++) {
        int vc = ct * 16 + n;
        size_t jrow = (size_t)((vc & 3) * 1024 + m0 + (vc >> 2));
        #pragma unroll
        for (int kc = 0; kc < 8; kc++) {
            wx[ct*8+kc] = *(const bf16x8*)&Wl[jrow*2048 +        w*256 + kc*32 + lk];
            wh[ct*8+kc] = *(const bf16x8*)&Wl[jrow*2048 + 1024 + w*256 + kc*32 + lk];
        }
    }

    // ---- epilogue ownership: thread -> (batch eb, m-pair em,em+1)
    const int eb = lane >> 1;
    const int q  = lane & 1;
    const int em = m0 + 4 * w + 2 * q;
    float bs0[4], bs1[4];
    #pragma unroll
    for (int gg = 0; gg < 4; gg++) {
        bs0[gg] = bih[l*4096 + gg*1024 + em]     + bhh[l*4096 + gg*1024 + em];
        bs1[gg] = bih[l*4096 + gg*1024 + em + 1] + bhh[l*4096 + gg*1024 + em + 1];
    }
    float2 creg = *(const float2*)&c0[(size_t)l * 32768 + eb * 1024 + em];
    float2 hlast = {0.f, 0.f};
    const int uh = eb >> 4, urow = eb & 15;

    // ---- staging: thread covers linear 16B chunks c=(tid+si*256) of tile
    // chunk coords: blk=w+4si, b=(tid>>1)&31, halfk=tid&1
    // LDS phys = b*2048 + ((blk*32 + halfk*16) ^ ((b&7)<<4))
    char* const bufb = (char*)&buf[0][0];
    const int sb  = (tid >> 1) & 31;
    char* const stL = bufb + sb * 2048
                    + ((w * 32 + (tid & 1) * 16) ^ ((sb & 7) << 4));

    // ---- frag read bases: phys = r*2048 + ((w*512+kc*64+g*16) ^ ((r&7)<<4))
    const int hb64 = (nn7 >> 2) * 64;
    const int gx16 = (g ^ (nn7 & 3)) * 16;
    const char* rA0 = bufb + n * 2048 + w * 512 + gx16 + hb64;        // even kc
    const char* rA1 = bufb + n * 2048 + w * 512 + gx16 + (64 - hb64); // odd  kc
    const char* rB0 = rA0 + 16 * 2048;
    const char* rB1 = rA1 + 16 * 2048;

    f32x4 acc0[4] = {}, acc1[4] = {};

    auto stage = [&](const char* tb, bool byp) {
        u32x4 hv[16];
        const char* gp = tb + tid * 16;
        if (byp) { STAGE_LOADS(" sc0 sc1") }
        else     { STAGE_LOADS("") }
        asm volatile("s_waitcnt vmcnt(0)" ::: "memory");
        #pragma unroll
        for (int si = 0; si < 16; si++)
            *(u32x4*)(stL + si * 128) = hv[si];
    };

    auto gemm = [&](const bf16x8* wf) {
        #pragma unroll
        for (int kc2 = 0; kc2 < 4; kc2++) {
            bf16x8 a0 = *(const bf16x8*)(rA0 + kc2 * 128);
            bf16x8 a1 = *(const bf16x8*)(rB0 + kc2 * 128);
            #pragma unroll
            for (int ct = 0; ct < 4; ct++) {
                acc0[ct] = __builtin_amdgcn_mfma_f32_16x16x32_bf16(a0, wf[ct*8+2*kc2], acc0[ct], 0,0,0);
                acc1[ct] = __builtin_amdgcn_mfma_f32_16x16x32_bf16(a1, wf[ct*8+2*kc2], acc1[ct], 0,0,0);
            }
            bf16x8 b0 = *(const bf16x8*)(rA1 + kc2 * 128);
            bf16x8 b1 = *(const bf16x8*)(rB1 + kc2 * 128);
            #pragma unroll
            for (int ct = 0; ct < 4; ct++) {
                acc0[ct] = __builtin_amdgcn_mfma_f32_16x16x32_bf16(b0, wf[ct*8+2*kc2+1], acc0[ct], 0,0,0);
                acc1[ct] = __builtin_amdgcn_mfma_f32_16x16x32_bf16(b1, wf[ct*8+2*kc2+1], acc1[ct], 0,0,0);
            }
        }
    };

    // ---- prologue: layer-0 stages x(0) partials (static input, no deps)
    if (l == 0) {
        stage((const char*)xT, false);
        __syncthreads();
        gemm(wx);
    }
    __syncthreads();   // protect prologue LDS reads from first act stage

    const int lag = l * 2;
    #pragma unroll 1
    for (int s = 0; s < 258; s++) {
        const int  t   = s - lag;
        const bool act = (t >= 0) && (t < 256);

        if (act) {
            // h(t-1): published in iteration <= s-1, visible via barrier
            const char* hb = (t == 0)
                ? (const char*)(h0T + (size_t)l * 32768)
                : (l == 0 ? (const char*)(seqT + (size_t)(t - 1) * 32768)
                          : (const char*)(hparT + (size_t)((t - 1) & 1) * 32768));
            stage(hb, true);
            __syncthreads();                                  // B1
            gemm(wh);
            {
                int r0 = g * 4;
                #pragma unroll
                for (int ct = 0; ct < 4; ct++) {
                    *(f32x4*)&gred[w][0][ct][n][r0] = acc0[ct];
                    *(f32x4*)&gred[w][1][ct][n][r0] = acc1[ct];
                }
            }
            __syncthreads();                                  // B2
            // reduce + cell update; thread's 8 gate cols: ct=w, n=8q+j
            float g8[8];
            #pragma unroll
            for (int j = 0; j < 8; j++) {
                g8[j] = (gred[0][uh][w][8*q+j][urow] + gred[1][uh][w][8*q+j][urow])
                      + (gred[2][uh][w][8*q+j][urow] + gred[3][uh][w][8*q+j][urow]);
            }
            float gi0 = g8[0] + bs0[0], gf0 = g8[1] + bs0[1];
            float gg0 = g8[2] + bs0[2], go0 = g8[3] + bs0[3];
            float gi1 = g8[4] + bs1[0], gf1 = g8[5] + bs1[1];
            float gg1 = g8[6] + bs1[2], go1 = g8[7] + bs1[3];

            float c0n = sigmoidf_fast(gf0) * creg.x + sigmoidf_fast(gi0) * tanhf_fast(gg0);
            float c1n = sigmoidf_fast(gf1) * creg.y + sigmoidf_fast(gi1) * tanhf_fast(gg1);
            float h0v = sigmoidf_fast(go0) * tanhf_fast(c0n);
            float h1v = sigmoidf_fast(go1) * tanhf_fast(c1n);
            creg.x = c0n; creg.y = c1n;
            hlast.x = h0v; hlast.y = h1v;

            unsigned hp = (unsigned)f2bf(h0v) | ((unsigned)f2bf(h1v) << 16);
            *(unsigned*)&hout_bf[eb][4*w + 2*q] = hp;
            if (l == 1) {
                float2 hv2 = {h0v, h1v};
                *(float2*)&hout_f[eb][4*w + 2*q] = hv2;
            }
            __syncthreads();                                  // B3
            if (tid < 64) {
                u32x4 v = *(const u32x4*)((const char*)&hout_bf[0][0] + tid * 16);
                const char* dp = (l == 0)
                    ? (const char*)(seqT  + (size_t)t * 32768)       + bidl * 1024 + tid * 16
                    : (const char*)(hparT + (size_t)(t & 1) * 32768) + bidl * 1024 + tid * 16;
                asm volatile("global_store_dwordx4 %0, %1, off sc0 sc1"
                             :: "v"(dp), "v"(v) : "memory");
                asm volatile("s_waitcnt vmcnt(0)" ::: "memory");
                if (tid == 0)
                    __hip_atomic_store(flags + l * 64 + bidl, (unsigned)(s + 1),
                                       __ATOMIC_RELAXED, __HIP_MEMORY_SCOPE_AGENT);
            } else if (l == 1 && tid < 192) {
                int u = tid - 64;
                f32x4 v = *(const f32x4*)((const char*)&hout_f[0][0] + u * 16);
                *(f32x4*)((char*)outT + (size_t)t * 131072 + bidl * 2048 + u * 16) = v;
            }
        } else if (tid == 0) {
            __hip_atomic_store(flags + l * 64 + bidl, (unsigned)(s + 1),
                               __ATOMIC_RELAXED, __HIP_MEMORY_SCOPE_AGENT);
        }

        // ---- tail: x/seq partials for t+1 (reads data published <= s-1)
        const int  tn   = t + 1;
        const bool xact = (tn >= ((l == 0) ? 1 : 0)) && (tn <= 255);
        if (xact) {
            stage(l == 0 ? (const char*)(xT   + (size_t)tn * 32768)
                         : (const char*)(seqT + (size_t)tn * 32768), l == 1);
            __syncthreads();                                  // B5
            #pragma unroll
            for (int ct = 0; ct < 4; ct++) {
                acc0[ct] = (f32x4){0.f, 0.f, 0.f, 0.f};
                acc1[ct] = (f32x4){0.f, 0.f, 0.f, 0.f};
            }
            gemm(wx);
        }

        // ---- global lockstep: all 128 flags >= s+1 (2 waves x 4 lines)
        if (tid < 128) pollge(flags + tid, (unsigned)(s + 1));
        __syncthreads();                                      // B6
    }

    // ---- final states
    float* hF = out + (size_t)8192 * 1024 + (size_t)l * 32768;
    float* cF = out + (size_t)8192 * 1024 + 65536 + (size_t)l * 32768;
    float2 hf2 = {hlast.x, hlast.y};
    *(float2*)&hF[eb * 1024 + em] = hf2;
    float2 cf2 = {creg.x, creg.y};
    *(float2*)&cF[eb * 1024 + em] = cf2;
}

extern "C" void kernel_launch(void* const* d_in, const int* in_sizes, int n_in,
                              void* d_out, int out_size, void* d_ws, size_t ws_size,
                              hipStream_t stream)
{
    const float* x   = (const float*)d_in[0];
    const float* h0  = (const float*)d_in[1];
    const float* c0  = (const float*)d_in[2];
    const float* Wih = (const float*)d_in[3];
    const float* Whh = (const float*)d_in[4];
    const float* bih = (const float*)d_in[5];
    const float* bhh = (const float*)d_in[6];
    float* out = (float*)d_out;

    char* p = (char*)d_ws;
    unsigned short* xT    = (unsigned short*)p; p += (size_t)256 * 32768 * 2;      // 16 MB
    unsigned short* seqT  = (unsigned short*)p; p += (size_t)256 * 32768 * 2;      // 16 MB
    unsigned short* Wcat  = (unsigned short*)p; p += (size_t)2 * 4096 * 2048 * 2;  // 32 MB
    unsigned short* h0T   = (unsigned short*)p; p += (size_t)2 * 32768 * 2;        // 128 KB
    unsigned short* hparT = (unsigned short*)p; p += (size_t)2 * 32768 * 2;        // 128 KB
    float*          outT  = (float*)p;          p += (size_t)256 * 32768 * 4;      // 32 MB
    unsigned int*   flags = (unsigned int*)p;   p += 4096;

    hipMemsetAsync(flags, 0, 4096, stream);
    cvt_w_concat<<<1024, 256, 0, stream>>>(Wih, Wcat, 0,    2 * 4096 * 256);
    cvt_w_concat<<<1024, 256, 0, stream>>>(Whh, Wcat, 1024, 2 * 4096 * 256);
    cvt_x_tiles<<<256, 256, 0, stream>>>(x, xT);
    cvt_h0_tiles<<<2, 256, 0, stream>>>(h0, h0T);

    lstm_fused<<<128, 256, 0, stream>>>(Wcat, xT, seqT, h0T, hparT, outT,
                                        c0, bih, bhh, out, flags);

    out_transpose<<<256, 256, 0, stream>>>(outT, out);
}